// Round 5
// baseline (188.374 us; speedup 1.0000x reference)
//
#include <hip/hip_runtime.h>
#include <math.h>

#define D_IN   1024
#define STACKN 4
#define BATCHN 8192
#define OUTW   (STACKN * D_IN)   // 4096

typedef int   iv2 __attribute__((ext_vector_type(2)));
typedef float fv4 __attribute__((ext_vector_type(4)));

__device__ __forceinline__ int   f2i(float x){ union{float f;int i;}u; u.f=x; return u.i; }
__device__ __forceinline__ float i2f(int x){ union{float f;int i;}u; u.i=x; return u.f; }

// DPP move: dst lane gets src lane per CTRL (quad_perm / row_ror), full masks.
template<int CTRL>
__device__ __forceinline__ float dpp_mov(float v){
    return i2f(__builtin_amdgcn_update_dpp(0, f2i(v), CTRL, 0xF, 0xF, false));
}

// Unnormalized FWHT-1024 over one wave, TWO rows stage-interleaved for ILP.
// element i = k*256 + lane*4 + c ; reg r = k*4 + c.
// i-bits: [1:0]=c (reg masks 1,2) [7:2]=lane [9:8]=k (reg masks 4,8).
// Cross-lane via DPP / ds_swizzle / permlane32_swap to spread work across
// VALU + DS pipes.
__device__ __forceinline__ void fwht1024x2(float a[16], float b[16],
                                           float sg1, float sg2, float sg4,
                                           float sg8, float sg16)
{
    // ---- register-local stages (i-bits 0,1,8,9) ----
    #pragma unroll
    for (int m = 1; m <= 8; m <<= 1) {
        #pragma unroll
        for (int r = 0; r < 16; ++r) {
            if (!(r & m)) {
                float x0 = a[r], x1 = a[r ^ m];
                a[r] = x0 + x1;  a[r ^ m] = x0 - x1;
                float y0 = b[r], y1 = b[r ^ m];
                b[r] = y0 + y1;  b[r ^ m] = y0 - y1;
            }
        }
    }
    // ---- lane xor 1: DPP quad_perm [1,0,3,2] ----
    #pragma unroll
    for (int r = 0; r < 16; ++r) {
        float ta = dpp_mov<0xB1>(a[r]); a[r] = fmaf(a[r], sg1, ta);
        float tb = dpp_mov<0xB1>(b[r]); b[r] = fmaf(b[r], sg1, tb);
    }
    // ---- lane xor 2: DPP quad_perm [2,3,0,1] ----
    #pragma unroll
    for (int r = 0; r < 16; ++r) {
        float ta = dpp_mov<0x4E>(a[r]); a[r] = fmaf(a[r], sg2, ta);
        float tb = dpp_mov<0x4E>(b[r]); b[r] = fmaf(b[r], sg2, tb);
    }
    // ---- lane xor 4: ds_swizzle BitMode xor=4 ----
    #pragma unroll
    for (int r = 0; r < 16; ++r) {
        float ta = i2f(__builtin_amdgcn_ds_swizzle(f2i(a[r]), 0x101F));
        float tb = i2f(__builtin_amdgcn_ds_swizzle(f2i(b[r]), 0x101F));
        a[r] = fmaf(a[r], sg4, ta);
        b[r] = fmaf(b[r], sg4, tb);
    }
    // ---- lane xor 8: DPP row_ror:8 ((l±8)%16 == l^8) ----
    #pragma unroll
    for (int r = 0; r < 16; ++r) {
        float ta = dpp_mov<0x128>(a[r]); a[r] = fmaf(a[r], sg8, ta);
        float tb = dpp_mov<0x128>(b[r]); b[r] = fmaf(b[r], sg8, tb);
    }
    // ---- lane xor 16: ds_swizzle BitMode xor=16 (DS pipe balance) ----
    #pragma unroll
    for (int r = 0; r < 16; ++r) {
        float ta = i2f(__builtin_amdgcn_ds_swizzle(f2i(a[r]), 0x401F));
        float tb = i2f(__builtin_amdgcn_ds_swizzle(f2i(b[r]), 0x401F));
        a[r] = fmaf(a[r], sg16, ta);
        b[r] = fmaf(b[r], sg16, tb);
    }
    // ---- lane xor 32: permlane32_swap pair trick (pure VALU) ----
    #pragma unroll
    for (int r = 0; r < 16; r += 2) {
        {
            iv2 p = __builtin_amdgcn_permlane32_swap(f2i(a[r]), f2i(a[r+1]), false, false);
            float u = i2f(p[0]), w = i2f(p[1]);
            float sum = u + w, dif = u - w;
            iv2 q = __builtin_amdgcn_permlane32_swap(f2i(sum), f2i(dif), false, false);
            a[r] = i2f(q[0]); a[r+1] = i2f(q[1]);
        }
        {
            iv2 p = __builtin_amdgcn_permlane32_swap(f2i(b[r]), f2i(b[r+1]), false, false);
            float u = i2f(p[0]), w = i2f(p[1]);
            float sum = u + w, dif = u - w;
            iv2 q = __builtin_amdgcn_permlane32_swap(f2i(sum), f2i(dif), false, false);
            b[r] = i2f(q[0]); b[r+1] = i2f(q[1]);
        }
    }
}

// Precompute g_tilde = g_mu + softplus(g_rho)*eps into workspace (4096 f32).
__global__ __launch_bounds__(256) void whvi_prep(
    const float* __restrict__ g_mu, const float* __restrict__ g_rho,
    const float* __restrict__ eps, float* __restrict__ gt)
{
    const int i = blockIdx.x * 256 + threadIdx.x;
    const float r  = g_rho[i];
    const float sp = fmaxf(r, 0.0f) + log1pf(expf(-fabsf(r)));
    gt[i] = fmaf(sp, eps[i], g_mu[i]);
}

// One wave = TWO batch rows, all 4 stacks. Params loaded once per stack for
// both rows; the two rows' FWHTs are stage-interleaved for ILP.
template<bool USE_WS>
__global__ __launch_bounds__(256, 4) void whvi_main(
    const float* __restrict__ x,
    const float* __restrict__ s1,
    const float* __restrict__ s2,
    const float* __restrict__ g_mu,
    const float* __restrict__ g_rho,
    const float* __restrict__ eps,
    const float* __restrict__ gt,
    float* __restrict__ out)
{
    const int lane = threadIdx.x & 63;
    const int row0 = (((blockIdx.x << 2) + (threadIdx.x >> 6)) << 1);

    const float sg1  = (lane & 1)  ? -1.0f : 1.0f;
    const float sg2  = (lane & 2)  ? -1.0f : 1.0f;
    const float sg4  = (lane & 4)  ? -1.0f : 1.0f;
    const float sg8  = (lane & 8)  ? -1.0f : 1.0f;
    const float sg16 = (lane & 16) ? -1.0f : 1.0f;

    // load both x rows once
    const float* __restrict__ xr0 = x + (size_t)row0 * D_IN;
    const float* __restrict__ xr1 = xr0 + D_IN;
    float xa[16], xb[16];
    #pragma unroll
    for (int k = 0; k < 4; ++k) {
        fv4 t0 = *(const fv4*)(xr0 + (k << 8) + (lane << 2));
        xa[k*4+0] = t0.x; xa[k*4+1] = t0.y; xa[k*4+2] = t0.z; xa[k*4+3] = t0.w;
        fv4 t1 = *(const fv4*)(xr1 + (k << 8) + (lane << 2));
        xb[k*4+0] = t1.x; xb[k*4+1] = t1.y; xb[k*4+2] = t1.z; xb[k*4+3] = t1.w;
    }

    float* __restrict__ orow0 = out + (size_t)row0 * OUTW;
    float* __restrict__ orow1 = orow0 + OUTW;

    #pragma unroll
    for (int s = 0; s < STACKN; ++s) {
        const int pb = s * D_IN + (lane << 2);
        float s2v[16], gv[16], s1v[16];
        #pragma unroll
        for (int k = 0; k < 4; ++k) {
            fv4 t2 = *(const fv4*)(s2 + pb + (k << 8));
            s2v[k*4+0] = t2.x; s2v[k*4+1] = t2.y; s2v[k*4+2] = t2.z; s2v[k*4+3] = t2.w;
            fv4 t1 = *(const fv4*)(s1 + pb + (k << 8));
            s1v[k*4+0] = t1.x; s1v[k*4+1] = t1.y; s1v[k*4+2] = t1.z; s1v[k*4+3] = t1.w;
            if (USE_WS) {
                fv4 tg = *(const fv4*)(gt + pb + (k << 8));
                gv[k*4+0] = tg.x; gv[k*4+1] = tg.y; gv[k*4+2] = tg.z; gv[k*4+3] = tg.w;
            } else {
                #pragma unroll
                for (int c = 0; c < 4; ++c) {
                    const int i = pb + (k << 8) + c;
                    const float rr = g_rho[i];
                    const float sp = fmaxf(rr, 0.0f) + log1pf(expf(-fabsf(rr)));
                    gv[k*4+c] = fmaf(sp, eps[i], g_mu[i]);
                }
            }
        }

        float va[16], vb[16];
        #pragma unroll
        for (int r = 0; r < 16; ++r) { va[r] = xa[r] * s2v[r]; vb[r] = xb[r] * s2v[r]; }

        fwht1024x2(va, vb, sg1, sg2, sg4, sg8, sg16);

        #pragma unroll
        for (int r = 0; r < 16; ++r) { va[r] *= gv[r]; vb[r] *= gv[r]; }

        fwht1024x2(va, vb, sg1, sg2, sg4, sg8, sg16);

        #pragma unroll
        for (int k = 0; k < 4; ++k) {
            fv4 ta;
            ta.x = va[k*4+0] * s1v[k*4+0];
            ta.y = va[k*4+1] * s1v[k*4+1];
            ta.z = va[k*4+2] * s1v[k*4+2];
            ta.w = va[k*4+3] * s1v[k*4+3];
            __builtin_nontemporal_store(ta, (fv4*)(orow0 + s * D_IN + (k << 8) + (lane << 2)));
            fv4 tb;
            tb.x = vb[k*4+0] * s1v[k*4+0];
            tb.y = vb[k*4+1] * s1v[k*4+1];
            tb.z = vb[k*4+2] * s1v[k*4+2];
            tb.w = vb[k*4+3] * s1v[k*4+3];
            __builtin_nontemporal_store(tb, (fv4*)(orow1 + s * D_IN + (k << 8) + (lane << 2)));
        }
    }
}

extern "C" void kernel_launch(void* const* d_in, const int* in_sizes, int n_in,
                              void* d_out, int out_size, void* d_ws, size_t ws_size,
                              hipStream_t stream) {
    const float* x     = (const float*)d_in[0];
    const float* s1    = (const float*)d_in[1];
    const float* s2    = (const float*)d_in[2];
    const float* g_mu  = (const float*)d_in[3];
    const float* g_rho = (const float*)d_in[4];
    const float* eps   = (const float*)d_in[5];
    float* out = (float*)d_out;

    const bool use_ws = ws_size >= (size_t)(STACKN * D_IN * sizeof(float));
    if (use_ws) {
        float* gt = (float*)d_ws;
        whvi_prep<<<STACKN * D_IN / 256, 256, 0, stream>>>(g_mu, g_rho, eps, gt);
        whvi_main<true><<<BATCHN / 8, 256, 0, stream>>>(x, s1, s2, g_mu, g_rho, eps, gt, out);
    } else {
        whvi_main<false><<<BATCHN / 8, 256, 0, stream>>>(x, s1, s2, g_mu, g_rho, eps, nullptr, out);
    }
}

// Round 7
// 184.166 us; speedup vs baseline: 1.0228x; 1.0228x over previous
//
#include <hip/hip_runtime.h>
#include <math.h>

#define D_IN   1024
#define STACKN 4
#define BATCHN 8192
#define OUTW   (STACKN * D_IN)   // 4096
#define ROWS_PER_WAVE 4

typedef int   iv2 __attribute__((ext_vector_type(2)));
typedef float fv4 __attribute__((ext_vector_type(4)));

__device__ __forceinline__ int   f2i(float x){ union{float f;int i;}u; u.f=x; return u.i; }
__device__ __forceinline__ float i2f(int x){ union{float f;int i;}u; u.i=x; return u.f; }

// DPP move: dst lane gets src lane per CTRL (quad_perm / row_ror), full masks.
template<int CTRL>
__device__ __forceinline__ float dpp_mov(float v){
    return i2f(__builtin_amdgcn_update_dpp(0, f2i(v), CTRL, 0xF, 0xF, false));
}

// Unnormalized FWHT-1024 over one wave (R2-proven mix).
// element i = k*256 + lane*4 + c ; reg r = k*4 + c.
// i-bits: [1:0]=c (reg masks 1,2) [7:2]=lane [9:8]=k (reg masks 4,8).
__device__ __forceinline__ void fwht1024(float v[16],
                                         float sg1, float sg2,
                                         float sg4, float sg8)
{
    // ---- register-local stages (i-bits 0,1,8,9) ----
    #pragma unroll
    for (int m = 1; m <= 8; m <<= 1) {
        #pragma unroll
        for (int r = 0; r < 16; ++r) {
            if (!(r & m)) {
                float a = v[r], b = v[r ^ m];
                v[r]     = a + b;
                v[r ^ m] = a - b;
            }
        }
    }
    // ---- lane xor 1: DPP quad_perm [1,0,3,2] ----
    #pragma unroll
    for (int r = 0; r < 16; ++r) {
        float t = dpp_mov<0xB1>(v[r]);
        v[r] = fmaf(v[r], sg1, t);
    }
    // ---- lane xor 2: DPP quad_perm [2,3,0,1] ----
    #pragma unroll
    for (int r = 0; r < 16; ++r) {
        float t = dpp_mov<0x4E>(v[r]);
        v[r] = fmaf(v[r], sg2, t);
    }
    // ---- lane xor 4: ds_swizzle BitMode xor=4 ----
    #pragma unroll
    for (int r = 0; r < 16; ++r) {
        float t = i2f(__builtin_amdgcn_ds_swizzle(f2i(v[r]), 0x101F));
        v[r] = fmaf(v[r], sg4, t);
    }
    // ---- lane xor 8: DPP row_ror:8 ((l±8)%16 == l^8) ----
    #pragma unroll
    for (int r = 0; r < 16; ++r) {
        float t = dpp_mov<0x128>(v[r]);
        v[r] = fmaf(v[r], sg8, t);
    }
    // ---- lane xor 16: permlane16_swap pair trick (VALU) ----
    #pragma unroll
    for (int r = 0; r < 16; r += 2) {
        iv2 p = __builtin_amdgcn_permlane16_swap(f2i(v[r]), f2i(v[r+1]), false, false);
        float a = i2f(p[0]), b = i2f(p[1]);
        float s = a + b, d = a - b;
        iv2 q = __builtin_amdgcn_permlane16_swap(f2i(s), f2i(d), false, false);
        v[r]   = i2f(q[0]);
        v[r+1] = i2f(q[1]);
    }
    // ---- lane xor 32: permlane32_swap pair trick (VALU) ----
    #pragma unroll
    for (int r = 0; r < 16; r += 2) {
        iv2 p = __builtin_amdgcn_permlane32_swap(f2i(v[r]), f2i(v[r+1]), false, false);
        float a = i2f(p[0]), b = i2f(p[1]);
        float s = a + b, d = a - b;
        iv2 q = __builtin_amdgcn_permlane32_swap(f2i(s), f2i(d), false, false);
        v[r]   = i2f(q[0]);
        v[r+1] = i2f(q[1]);
    }
}

// Precompute g_tilde = g_mu + softplus(g_rho)*eps into workspace (4096 f32).
__global__ __launch_bounds__(256) void whvi_prep(
    const float* __restrict__ g_mu, const float* __restrict__ g_rho,
    const float* __restrict__ eps, float* __restrict__ gt)
{
    const int i = blockIdx.x * 256 + threadIdx.x;
    const float r  = g_rho[i];
    const float sp = fmaxf(r, 0.0f) + log1pf(expf(-fabsf(r)));
    gt[i] = fmaf(sp, eps[i], g_mu[i]);
}

// Persistent per-stack waves: each wave owns ONE stack (params register-
// resident, loaded once) and processes ROWS_PER_WAVE consecutive rows with
// next-row register prefetch to hide x-load latency.
template<bool USE_WS>
__global__ __launch_bounds__(256) void whvi_main(
    const float* __restrict__ x,
    const float* __restrict__ s1,
    const float* __restrict__ s2,
    const float* __restrict__ g_mu,
    const float* __restrict__ g_rho,
    const float* __restrict__ eps,
    const float* __restrict__ gt,
    float* __restrict__ out)
{
    const int lane  = threadIdx.x & 63;
    const int stack = blockIdx.y;
    const int wave  = blockIdx.x * 4 + (threadIdx.x >> 6);   // 0..2047 per stack
    const int row0  = wave * ROWS_PER_WAVE;

    const float sg1 = (lane & 1) ? -1.0f : 1.0f;
    const float sg2 = (lane & 2) ? -1.0f : 1.0f;
    const float sg4 = (lane & 4) ? -1.0f : 1.0f;
    const float sg8 = (lane & 8) ? -1.0f : 1.0f;

    // ---- per-stack params, register-resident for the whole wave lifetime ----
    const int pb = stack * D_IN + (lane << 2);
    float s2v[16], gv[16], s1v[16];
    #pragma unroll
    for (int k = 0; k < 4; ++k) {
        fv4 t2 = *(const fv4*)(s2 + pb + (k << 8));
        s2v[k*4+0] = t2.x; s2v[k*4+1] = t2.y; s2v[k*4+2] = t2.z; s2v[k*4+3] = t2.w;
        fv4 t1 = *(const fv4*)(s1 + pb + (k << 8));
        s1v[k*4+0] = t1.x; s1v[k*4+1] = t1.y; s1v[k*4+2] = t1.z; s1v[k*4+3] = t1.w;
        if (USE_WS) {
            fv4 tg = *(const fv4*)(gt + pb + (k << 8));
            gv[k*4+0] = tg.x; gv[k*4+1] = tg.y; gv[k*4+2] = tg.z; gv[k*4+3] = tg.w;
        } else {
            #pragma unroll
            for (int c = 0; c < 4; ++c) {
                const int i = pb + (k << 8) + c;
                const float rr = g_rho[i];
                const float sp = fmaxf(rr, 0.0f) + log1pf(expf(-fabsf(rr)));
                gv[k*4+c] = fmaf(sp, eps[i], g_mu[i]);
            }
        }
    }

    // ---- prime the pipeline: load row0 ----
    float cur[16];
    {
        const float* __restrict__ xr = x + (size_t)row0 * D_IN;
        #pragma unroll
        for (int k = 0; k < 4; ++k) {
            fv4 t = *(const fv4*)(xr + (k << 8) + (lane << 2));
            cur[k*4+0] = t.x; cur[k*4+1] = t.y; cur[k*4+2] = t.z; cur[k*4+3] = t.w;
        }
    }

    #pragma unroll
    for (int i = 0; i < ROWS_PER_WAVE; ++i) {
        const int row = row0 + i;

        // prefetch next row while this row computes
        float nxt[16];
        if (i < ROWS_PER_WAVE - 1) {
            const float* __restrict__ xr = x + (size_t)(row + 1) * D_IN;
            #pragma unroll
            for (int k = 0; k < 4; ++k) {
                fv4 t = *(const fv4*)(xr + (k << 8) + (lane << 2));
                nxt[k*4+0] = t.x; nxt[k*4+1] = t.y; nxt[k*4+2] = t.z; nxt[k*4+3] = t.w;
            }
        }

        float v[16];
        #pragma unroll
        for (int r = 0; r < 16; ++r) v[r] = cur[r] * s2v[r];

        fwht1024(v, sg1, sg2, sg4, sg8);

        #pragma unroll
        for (int r = 0; r < 16; ++r) v[r] *= gv[r];

        fwht1024(v, sg1, sg2, sg4, sg8);

        float* __restrict__ orow = out + (size_t)row * OUTW + stack * D_IN;
        #pragma unroll
        for (int k = 0; k < 4; ++k) {
            fv4 t;
            t.x = v[k*4+0] * s1v[k*4+0];
            t.y = v[k*4+1] * s1v[k*4+1];
            t.z = v[k*4+2] * s1v[k*4+2];
            t.w = v[k*4+3] * s1v[k*4+3];
            *(fv4*)(orow + (k << 8) + (lane << 2)) = t;
        }

        if (i < ROWS_PER_WAVE - 1) {
            #pragma unroll
            for (int r = 0; r < 16; ++r) cur[r] = nxt[r];
        }
    }
}

extern "C" void kernel_launch(void* const* d_in, const int* in_sizes, int n_in,
                              void* d_out, int out_size, void* d_ws, size_t ws_size,
                              hipStream_t stream) {
    const float* x     = (const float*)d_in[0];
    const float* s1    = (const float*)d_in[1];
    const float* s2    = (const float*)d_in[2];
    const float* g_mu  = (const float*)d_in[3];
    const float* g_rho = (const float*)d_in[4];
    const float* eps   = (const float*)d_in[5];
    float* out = (float*)d_out;

    // grid: (BATCHN / ROWS_PER_WAVE / 4 waves) blocks in x, STACKN in y.
    dim3 grid(BATCHN / ROWS_PER_WAVE / 4, STACKN);

    const bool use_ws = ws_size >= (size_t)(STACKN * D_IN * sizeof(float));
    if (use_ws) {
        float* gt = (float*)d_ws;
        whvi_prep<<<STACKN * D_IN / 256, 256, 0, stream>>>(g_mu, g_rho, eps, gt);
        whvi_main<true><<<grid, 256, 0, stream>>>(x, s1, s2, g_mu, g_rho, eps, gt, out);
    } else {
        whvi_main<false><<<grid, 256, 0, stream>>>(x, s1, s2, g_mu, g_rho, eps, nullptr, out);
    }
}

// Round 8
// 176.554 us; speedup vs baseline: 1.0669x; 1.0431x over previous
//
#include <hip/hip_runtime.h>
#include <math.h>

#define D_IN   1024
#define STACKN 4
#define BATCHN 8192
#define OUTW   (STACKN * D_IN)   // 4096

typedef int   iv2 __attribute__((ext_vector_type(2)));
typedef float fv4 __attribute__((ext_vector_type(4)));

__device__ __forceinline__ int   f2i(float x){ union{float f;int i;}u; u.f=x; return u.i; }
__device__ __forceinline__ float i2f(int x){ union{float f;int i;}u; u.i=x; return u.f; }

// DPP move: dst lane gets src lane per CTRL (quad_perm / row_ror), full masks.
template<int CTRL>
__device__ __forceinline__ float dpp_mov(float v){
    return i2f(__builtin_amdgcn_update_dpp(0, f2i(v), CTRL, 0xF, 0xF, false));
}

// Unnormalized FWHT-1024 over one wave (R2-proven mix).
// element i = k*256 + lane*4 + c ; reg r = k*4 + c.
// i-bits: [1:0]=c (reg masks 1,2) [7:2]=lane [9:8]=k (reg masks 4,8).
__device__ __forceinline__ void fwht1024(float v[16],
                                         float sg1, float sg2,
                                         float sg4, float sg8)
{
    // ---- register-local stages (i-bits 0,1,8,9) ----
    #pragma unroll
    for (int m = 1; m <= 8; m <<= 1) {
        #pragma unroll
        for (int r = 0; r < 16; ++r) {
            if (!(r & m)) {
                float a = v[r], b = v[r ^ m];
                v[r]     = a + b;
                v[r ^ m] = a - b;
            }
        }
    }
    // ---- lane xor 1: DPP quad_perm [1,0,3,2] ----
    #pragma unroll
    for (int r = 0; r < 16; ++r) {
        float t = dpp_mov<0xB1>(v[r]);
        v[r] = fmaf(v[r], sg1, t);
    }
    // ---- lane xor 2: DPP quad_perm [2,3,0,1] ----
    #pragma unroll
    for (int r = 0; r < 16; ++r) {
        float t = dpp_mov<0x4E>(v[r]);
        v[r] = fmaf(v[r], sg2, t);
    }
    // ---- lane xor 4: ds_swizzle BitMode xor=4 ----
    #pragma unroll
    for (int r = 0; r < 16; ++r) {
        float t = i2f(__builtin_amdgcn_ds_swizzle(f2i(v[r]), 0x101F));
        v[r] = fmaf(v[r], sg4, t);
    }
    // ---- lane xor 8: DPP row_ror:8 ((l±8)%16 == l^8) ----
    #pragma unroll
    for (int r = 0; r < 16; ++r) {
        float t = dpp_mov<0x128>(v[r]);
        v[r] = fmaf(v[r], sg8, t);
    }
    // ---- lane xor 16: permlane16_swap pair trick (VALU) ----
    #pragma unroll
    for (int r = 0; r < 16; r += 2) {
        iv2 p = __builtin_amdgcn_permlane16_swap(f2i(v[r]), f2i(v[r+1]), false, false);
        float a = i2f(p[0]), b = i2f(p[1]);
        float s = a + b, d = a - b;
        iv2 q = __builtin_amdgcn_permlane16_swap(f2i(s), f2i(d), false, false);
        v[r]   = i2f(q[0]);
        v[r+1] = i2f(q[1]);
    }
    // ---- lane xor 32: permlane32_swap pair trick (VALU) ----
    #pragma unroll
    for (int r = 0; r < 16; r += 2) {
        iv2 p = __builtin_amdgcn_permlane32_swap(f2i(v[r]), f2i(v[r+1]), false, false);
        float a = i2f(p[0]), b = i2f(p[1]);
        float s = a + b, d = a - b;
        iv2 q = __builtin_amdgcn_permlane32_swap(f2i(s), f2i(d), false, false);
        v[r]   = i2f(q[0]);
        v[r+1] = i2f(q[1]);
    }
}

// Precompute g_tilde = g_mu + softplus(g_rho)*eps into workspace (4096 f32).
__global__ __launch_bounds__(256) void whvi_prep(
    const float* __restrict__ g_mu, const float* __restrict__ g_rho,
    const float* __restrict__ eps, float* __restrict__ gt)
{
    const int i = blockIdx.x * 256 + threadIdx.x;
    const float r  = g_rho[i];
    const float sp = fmaxf(r, 0.0f) + log1pf(expf(-fabsf(r)));
    gt[i] = fmaf(sp, eps[i], g_mu[i]);
}

// One wave = one (row, stack) task. Minimal register lifetime + software
// pipelining: gt loads issue before FWHT#1 (used after), s1 loads issue
// before FWHT#2 (used after) — each ~300cy latency hides under ~480cy of
// FWHT VALU. __launch_bounds__(256,8) caps VGPR at 64 -> 8 waves/SIMD.
template<bool USE_WS>
__global__ __launch_bounds__(256, 8) void whvi_main(
    const float* __restrict__ x,
    const float* __restrict__ s1,
    const float* __restrict__ s2,
    const float* __restrict__ g_mu,
    const float* __restrict__ g_rho,
    const float* __restrict__ eps,
    const float* __restrict__ gt,
    float* __restrict__ out)
{
    const int lane  = threadIdx.x & 63;
    const int stack = blockIdx.y;
    const int row   = (blockIdx.x << 2) + (threadIdx.x >> 6);

    const float sg1 = (lane & 1) ? -1.0f : 1.0f;
    const float sg2 = (lane & 2) ? -1.0f : 1.0f;
    const float sg4 = (lane & 4) ? -1.0f : 1.0f;
    const float sg8 = (lane & 8) ? -1.0f : 1.0f;

    const int pb = stack * D_IN + (lane << 2);
    const float* __restrict__ xr = x + (size_t)row * D_IN;

    // ---- load x and s2, fuse the multiply (s2 regs die immediately) ----
    float v[16];
    #pragma unroll
    for (int k = 0; k < 4; ++k) {
        fv4 xt = *(const fv4*)(xr + (k << 8) + (lane << 2));
        fv4 st = *(const fv4*)(s2 + pb + (k << 8));
        v[k*4+0] = xt.x * st.x;
        v[k*4+1] = xt.y * st.y;
        v[k*4+2] = xt.z * st.z;
        v[k*4+3] = xt.w * st.w;
    }

    // ---- issue gt loads now; first use is after FWHT#1 ----
    float gv[16];
    #pragma unroll
    for (int k = 0; k < 4; ++k) {
        if (USE_WS) {
            fv4 tg = *(const fv4*)(gt + pb + (k << 8));
            gv[k*4+0] = tg.x; gv[k*4+1] = tg.y; gv[k*4+2] = tg.z; gv[k*4+3] = tg.w;
        } else {
            #pragma unroll
            for (int c = 0; c < 4; ++c) {
                const int i = pb + (k << 8) + c;
                const float rr = g_rho[i];
                const float sp = fmaxf(rr, 0.0f) + log1pf(expf(-fabsf(rr)));
                gv[k*4+c] = fmaf(sp, eps[i], g_mu[i]);
            }
        }
    }

    fwht1024(v, sg1, sg2, sg4, sg8);

    #pragma unroll
    for (int r = 0; r < 16; ++r) v[r] *= gv[r];

    // ---- issue s1 loads now; first use is after FWHT#2 ----
    float s1v[16];
    #pragma unroll
    for (int k = 0; k < 4; ++k) {
        fv4 t1 = *(const fv4*)(s1 + pb + (k << 8));
        s1v[k*4+0] = t1.x; s1v[k*4+1] = t1.y; s1v[k*4+2] = t1.z; s1v[k*4+3] = t1.w;
    }

    fwht1024(v, sg1, sg2, sg4, sg8);

    float* __restrict__ orow = out + (size_t)row * OUTW + stack * D_IN;
    #pragma unroll
    for (int k = 0; k < 4; ++k) {
        fv4 t;
        t.x = v[k*4+0] * s1v[k*4+0];
        t.y = v[k*4+1] * s1v[k*4+1];
        t.z = v[k*4+2] * s1v[k*4+2];
        t.w = v[k*4+3] * s1v[k*4+3];
        *(fv4*)(orow + (k << 8) + (lane << 2)) = t;
    }
}

extern "C" void kernel_launch(void* const* d_in, const int* in_sizes, int n_in,
                              void* d_out, int out_size, void* d_ws, size_t ws_size,
                              hipStream_t stream) {
    const float* x     = (const float*)d_in[0];
    const float* s1    = (const float*)d_in[1];
    const float* s2    = (const float*)d_in[2];
    const float* g_mu  = (const float*)d_in[3];
    const float* g_rho = (const float*)d_in[4];
    const float* eps   = (const float*)d_in[5];
    float* out = (float*)d_out;

    // wave = (row, stack): grid (BATCHN/4, STACKN), 4 waves/block.
    dim3 grid(BATCHN / 4, STACKN);

    const bool use_ws = ws_size >= (size_t)(STACKN * D_IN * sizeof(float));
    if (use_ws) {
        float* gt = (float*)d_ws;
        whvi_prep<<<STACKN * D_IN / 256, 256, 0, stream>>>(g_mu, g_rho, eps, gt);
        whvi_main<true><<<grid, 256, 0, stream>>>(x, s1, s2, g_mu, g_rho, eps, gt, out);
    } else {
        whvi_main<false><<<grid, 256, 0, stream>>>(x, s1, s2, g_mu, g_rho, eps, nullptr, out);
    }
}